// Round 5
// baseline (170.749 us; speedup 1.0000x reference)
//
#include <hip/hip_runtime.h>

// WaveCell FDTD step, fp32, B=8, NY=NX=1024.
// y = inv*(8*h1 - (4-2b)*h2 + c^2*lap),  b = bg + rho/(1+h1^2),
// c = c_linear + 0.01*rho*h1^2, inv = 1/(4+2b), lap = 5pt zero-pad stencil.
// Outputs concatenated: [y (8M floats), h1 copy (8M floats)].
//
// R7: sustained-streaming pipeline. R4 (burst) and R6 (2x burst) tied at
// ~43 us / 3.2 TB/s with occupancy 30..65% all equivalent -> per-wave burst
// MLP and occupancy are not the levers. Last untested difference vs the
// 6.3 TB/s copy ubench: wave lifetime. Here each block owns 4 rows and
// software-pipelines: streams for row i+1 and h1 row i+2 are in flight
// while row i computes/stores; h1 column rolls through registers.
// Horizontal halo via in-wave shuffles + 2 prefetched boundary dwords
// (removes 2 wave-loads/row). Cache policy = R4 best: nt stores, nt loads
// h2/cl/rho, plain h1/bg. XCD swizzle: XCD x owns rows [x*128,(x+1)*128)
// for all batches.

typedef float f4 __attribute__((ext_vector_type(4)));

#define NX4   256      // float4 per row
#define NYDIM 1024

__device__ __forceinline__ float wave_pt(float h1x, float h2x, float clx,
                                         float rx, float bgx, float lap) {
    float s   = h1x * h1x;
    float b   = bgx + rx * __builtin_amdgcn_rcpf(1.0f + s);
    float c   = clx + 0.01f * rx * s;
    float inv = __builtin_amdgcn_rcpf(4.0f + 2.0f * b);
    return inv * (8.0f * h1x - (4.0f - 2.0f * b) * h2x + c * c * lap);
}

__global__ __launch_bounds__(256, 4) void wavecell_kernel(
    const f4* __restrict__ h1,
    const f4* __restrict__ h2,
    const f4* __restrict__ cl,
    const f4* __restrict__ rho,
    const f4* __restrict__ bg,
    f4*       __restrict__ out,
    int n4)   // total float4 groups = B*NY*NX/4 = 2,097,152
{
    const int tid  = threadIdx.x;            // f4-column 0..255
    const int lane = tid & 63;
    const int bi   = blockIdx.x;             // 0..2047: one block = 4 rows
    const int xcd  = bi & 7;
    const int j    = bi >> 3;                // 0..255
    const int q    = j & 31;                 // row-quad within XCD slice
    const int bat  = j >> 5;                 // batch 0..7
    const int gy0  = (xcd << 7) | (q << 2);  // first row: 0..1020
    const int g0   = (bat << 18) + (gy0 << 8) + tid;
    const float* h1f = (const float*)h1;
    const f4 z = {0.f, 0.f, 0.f, 0.f};

    // ---- prologue: row 0 working set + row 1 prefetch ----
    f4 up  = (gy0 > 0) ? h1[g0 - NX4] : z;   // row gy0-1
    f4 cc  = h1[g0];                          // row gy0
    f4 dn  = h1[g0 + NX4];                    // row gy0+1 (<=1021, always valid)
    f4 sh2 = __builtin_nontemporal_load(h2 + g0);
    f4 scl = __builtin_nontemporal_load(cl + g0);
    f4 srh = __builtin_nontemporal_load(rho + g0);
    f4 sbg = bg[(gy0 << 8) + tid];
    float bL = 0.f, bR = 0.f;                 // wave-boundary halo dwords
    if (lane == 0  && tid > 0)       bL = h1f[4 * g0 - 1];
    if (lane == 63 && tid < NX4 - 1) bR = h1f[4 * g0 + 4];

    const int g1 = g0 + NX4;
    f4 ph2 = __builtin_nontemporal_load(h2 + g1);
    f4 pcl = __builtin_nontemporal_load(cl + g1);
    f4 prh = __builtin_nontemporal_load(rho + g1);
    f4 pbg = bg[((gy0 + 1) << 8) + tid];
    f4 pdn = h1[g0 + 2 * NX4];                // row gy0+2 (<=1022, valid)
    float pbL = 0.f, pbR = 0.f;
    if (lane == 0  && tid > 0)       pbL = h1f[4 * g1 - 1];
    if (lane == 63 && tid < NX4 - 1) pbR = h1f[4 * g1 + 4];

    #pragma unroll
    for (int i = 0; i < 4; ++i) {
        const int g = g0 + i * NX4;

        // horizontal halo: in-wave shuffle; boundary lanes use prefetched dwords
        float L = __shfl_up(cc.w, 1);
        float R = __shfl_down(cc.x, 1);
        if (lane == 0)  L = bL;
        if (lane == 63) R = bR;

        float lapx = up.x + dn.x + L    + cc.y - 4.0f * cc.x;
        float lapy = up.y + dn.y + cc.x + cc.z - 4.0f * cc.y;
        float lapz = up.z + dn.z + cc.y + cc.w - 4.0f * cc.z;
        float lapw = up.w + dn.w + cc.z + R    - 4.0f * cc.w;

        f4 yv;
        yv.x = wave_pt(cc.x, sh2.x, scl.x, srh.x, sbg.x, lapx);
        yv.y = wave_pt(cc.y, sh2.y, scl.y, srh.y, sbg.y, lapy);
        yv.z = wave_pt(cc.z, sh2.z, scl.z, srh.z, sbg.z, lapz);
        yv.w = wave_pt(cc.w, sh2.w, scl.w, srh.w, sbg.w, lapw);

        __builtin_nontemporal_store(yv, out + g);        // y
        __builtin_nontemporal_store(cc, out + n4 + g);   // h1 copy

        if (i < 3) {
            // rotate pipeline
            up = cc; cc = dn; dn = pdn;
            sh2 = ph2; scl = pcl; srh = prh; sbg = pbg;
            bL = pbL; bR = pbR;
            if (i < 2) {       // prefetch streams for row i+2 (last needed: 3)
                const int gn = g0 + (i + 2) * NX4;
                ph2 = __builtin_nontemporal_load(h2 + gn);
                pcl = __builtin_nontemporal_load(cl + gn);
                prh = __builtin_nontemporal_load(rho + gn);
                pbg = bg[((gy0 + i + 2) << 8) + tid];
                pbL = 0.f; pbR = 0.f;
                if (lane == 0  && tid > 0)       pbL = h1f[4 * gn - 1];
                if (lane == 63 && tid < NX4 - 1) pbR = h1f[4 * gn + 4];
            }
            // prefetch h1 column: row i+3 (dn for the row after next)
            if (i == 0) pdn = h1[g0 + 3 * NX4];                       // row gy0+3
            if (i == 1) pdn = (gy0 + 4 < NYDIM) ? h1[g0 + 4 * NX4] : z; // row gy0+4
        }
    }
}

extern "C" void kernel_launch(void* const* d_in, const int* in_sizes, int n_in,
                              void* d_out, int out_size, void* d_ws, size_t ws_size,
                              hipStream_t stream) {
    const f4* h1  = (const f4*)d_in[0];
    const f4* h2  = (const f4*)d_in[1];
    const f4* cl  = (const f4*)d_in[2];
    const f4* rho = (const f4*)d_in[3];
    const f4* bg  = (const f4*)d_in[4];
    f4* out = (f4*)d_out;

    int n  = in_sizes[0];          // 8*1024*1024
    int n4 = n / 4;                // 2,097,152 float4 groups
    // grid: 8 batches x 256 row-quads = 2048 blocks (8 per CU)
    wavecell_kernel<<<2048, 256, 0, stream>>>(h1, h2, cl, rho, bg, out, n4);
}